// Round 5
// baseline (634.463 us; speedup 1.0000x reference)
//
#include <hip/hip_runtime.h>
#include <hip/hip_bf16.h>
#include <math.h>

static constexpr int N = 50000;
static constexpr int E = 800000;
static constexpr int F = 128;
static constexpr int H = 64;
static constexpr int G = 512;
static constexpr int C = 10;
static constexpr int CAP = 256;    // per-graph capacity for score-tied edges (full-32-bit ties ~never)

static inline int cdiv(long a, int b) { return (int)((a + b - 1) / b); }

// ---- deg (in-deg over dst) + seg + per-graph edge count via LDS hist ----
__global__ void k_deg_seg(const int* __restrict__ src, const int* __restrict__ dst,
                          const int* __restrict__ batch, int* __restrict__ deg,
                          int* __restrict__ seg, int* __restrict__ mcnt) {
  __shared__ int h[G];
  for (int i = threadIdx.x; i < G; i += 256) h[i] = 0;
  __syncthreads();
  for (int e = blockIdx.x * 256 + threadIdx.x; e < E; e += gridDim.x * 256) {
    atomicAdd(&deg[dst[e]], 1);
    int g = batch[src[e]];
    seg[e] = g;
    atomicAdd(&h[g], 1);
  }
  __syncthreads();
  for (int i = threadIdx.x; i < G; i += 256) {
    int v = h[i];
    if (v) atomicAdd(&mcnt[i], v);
  }
}

// ---- graph offsets by boundary detection on sorted batch ----
__global__ void k_goff(const int* __restrict__ batch, int* __restrict__ goff) {
  int i = blockIdx.x * 256 + threadIdx.x;
  if (i >= N) return;
  int b = batch[i];
  if (i == 0) {
    for (int g = 0; g <= b; ++g) goff[g] = 0;
  } else {
    int p = batch[i - 1];
    for (int g = p + 1; g <= b; ++g) goff[g] = i;
  }
  if (i == N - 1) {
    for (int g = b + 1; g <= G; ++g) goff[g] = N;
  }
}

// ---- single-block exclusive scan, shuffle-based; writes off[] and cursor[] ----
__global__ void k_excl_scan(const int* __restrict__ cnt, int* __restrict__ off,
                            int* __restrict__ cursor, int n) {
  __shared__ int wsum[16];
  __shared__ int carry;
  int tid = threadIdx.x, lane = tid & 63, wv = tid >> 6;
  if (tid == 0) carry = 0;
  __syncthreads();
  for (int base = 0; base < n; base += 4096) {
    int idx = base + tid * 4;
    int v0 = (idx + 0 < n) ? cnt[idx + 0] : 0;
    int v1 = (idx + 1 < n) ? cnt[idx + 1] : 0;
    int v2 = (idx + 2 < n) ? cnt[idx + 2] : 0;
    int v3 = (idx + 3 < n) ? cnt[idx + 3] : 0;
    int local = v0 + v1 + v2 + v3;
    int inc = local;
    for (int d = 1; d < 64; d <<= 1) {
      int t = __shfl_up(inc, d);
      if (lane >= d) inc += t;
    }
    if (lane == 63) wsum[wv] = inc;
    __syncthreads();
    if (tid < 16) {
      int t = wsum[tid];
      for (int d = 1; d < 16; d <<= 1) {
        int u = __shfl_up(t, d);
        if (tid >= d) t += u;
      }
      wsum[tid] = t;
    }
    __syncthreads();
    int woff = (wv > 0) ? wsum[wv - 1] : 0;
    int excl = carry + woff + inc - local;
    if (idx + 0 < n) { off[idx + 0] = excl;                cursor[idx + 0] = excl; }
    if (idx + 1 < n) { off[idx + 1] = excl + v0;           cursor[idx + 1] = excl + v0; }
    if (idx + 2 < n) { off[idx + 2] = excl + v0 + v1;      cursor[idx + 2] = excl + v0 + v1; }
    if (idx + 3 < n) { off[idx + 3] = excl + v0 + v1 + v2; cursor[idx + 3] = excl + v0 + v1 + v2; }
    int total = wsum[15];
    __syncthreads();
    if (tid == 0) carry += total;
    __syncthreads();
  }
  if (threadIdx.x == 0) off[n] = carry;
}

// ---- counting-sort fill: CSR entries {src, eid} by dst (single 8B scatter) ----
__global__ void k_fill_csr(const int* __restrict__ src, const int* __restrict__ dst,
                           int* __restrict__ cursor, int2* __restrict__ csr) {
  int e = blockIdx.x * 256 + threadIdx.x;
  if (e >= E) return;
  int slot = atomicAdd(&cursor[dst[e]], 1);
  csr[slot] = make_int2(src[e], e);
}

// ---- dense pre-GEMM (fp32 y): y = in@Wl, r = in@Wr + b ----
template <int K>
__global__ void k_gemm2(const float* __restrict__ in, const float* __restrict__ Wl,
                        const float* __restrict__ Wr, const float* __restrict__ b,
                        float* __restrict__ y, float* __restrict__ r) {
  __shared__ float sx[16][K];
  int lane = threadIdx.x, ty = threadIdx.y;
  int tid = ty * 64 + lane;
  int row0 = blockIdx.x * 16;
  const float4* gsrc = (const float4*)(in + (size_t)row0 * K);
  float4* sdst = (float4*)(&sx[0][0]);
#pragma unroll
  for (int i = tid; i < 16 * K / 4; i += 256) sdst[i] = gsrc[i];
  __syncthreads();
  float al[4], ar[4];
  float bias = b[lane];
#pragma unroll
  for (int j = 0; j < 4; ++j) { al[j] = 0.f; ar[j] = bias; }
#pragma unroll 4
  for (int f = 0; f < K; ++f) {
    float wl = Wl[f * H + lane];
    float wr = Wr[f * H + lane];
#pragma unroll
    for (int j = 0; j < 4; ++j) {
      float xv = sx[ty * 4 + j][f];
      al[j] += xv * wl;
      ar[j] += xv * wr;
    }
  }
#pragma unroll
  for (int j = 0; j < 4; ++j) {
    int row = row0 + ty * 4 + j;
    y[(size_t)row * H + lane] = al[j];
    r[(size_t)row * H + lane] = ar[j];
  }
}

// ---- dense pre-GEMM (bf16 y for the gather table): layers 2/3 ----
template <int K>
__global__ void k_gemm2h(const float* __restrict__ in, const float* __restrict__ Wl,
                         const float* __restrict__ Wr, const float* __restrict__ b,
                         __hip_bfloat16* __restrict__ y, float* __restrict__ r) {
  __shared__ float sx[16][K];
  int lane = threadIdx.x, ty = threadIdx.y;
  int tid = ty * 64 + lane;
  int row0 = blockIdx.x * 16;
  const float4* gsrc = (const float4*)(in + (size_t)row0 * K);
  float4* sdst = (float4*)(&sx[0][0]);
#pragma unroll
  for (int i = tid; i < 16 * K / 4; i += 256) sdst[i] = gsrc[i];
  __syncthreads();
  float al[4], ar[4];
  float bias = b[lane];
#pragma unroll
  for (int j = 0; j < 4; ++j) { al[j] = 0.f; ar[j] = bias; }
#pragma unroll 4
  for (int f = 0; f < K; ++f) {
    float wl = Wl[f * H + lane];
    float wr = Wr[f * H + lane];
#pragma unroll
    for (int j = 0; j < 4; ++j) {
      float xv = sx[ty * 4 + j][f];
      al[j] += xv * wl;
      ar[j] += xv * wr;
    }
  }
#pragma unroll
  for (int j = 0; j < 4; ++j) {
    int row = row0 + ty * 4 + j;
    y[(size_t)row * H + lane] = __float2bfloat16(al[j]);
    r[(size_t)row * H + lane] = ar[j];
  }
}

// ---- layer-1 aggregation (fp32 rows). Half-waves take alternate edges:
// lane = 32*half + c; each half reads a full 256B row (32 lanes x float2),
// combine across halves with shfl_xor(32). 2x unroll -> 4 rows in flight.
__global__ void k_agg1(const float* __restrict__ y, const float* __restrict__ r,
                       const int2* __restrict__ csr, const int* __restrict__ off,
                       float* __restrict__ out) {
  int node = blockIdx.x * 8 + threadIdx.y;
  int lane = threadIdx.x;
  int half = lane >> 5, c = lane & 31;
  int s0 = off[node], s1 = off[node + 1];
  float a0 = 0.f, a1 = 0.f;
  int i = s0 + half;
  for (; i + 2 < s1; i += 4) {
    int2 se0 = csr[i];
    int2 se1 = csr[i + 2];
    const float2* p0 = (const float2*)(y + (size_t)se0.x * H) + c;
    const float2* p1 = (const float2*)(y + (size_t)se1.x * H) + c;
    float2 v0 = *p0, v1 = *p1;
    a0 += v0.x + v1.x;
    a1 += v0.y + v1.y;
  }
  for (; i < s1; i += 2) {
    int2 se = csr[i];
    float2 v = *((const float2*)(y + (size_t)se.x * H) + c);
    a0 += v.x; a1 += v.y;
  }
  a0 += __shfl_xor(a0, 32);
  a1 += __shfl_xor(a1, 32);
  if (half == 0) {
    float inv = 1.f / fmaxf((float)(s1 - s0), 1.f);
    float2 rr = *((const float2*)(r + (size_t)node * H) + c);
    float2 o;
    o.x = fmaxf(a0 * inv + rr.x, 0.f);
    o.y = fmaxf(a1 * inv + rr.y, 0.f);
    *((float2*)(out + (size_t)node * H) + c) = o;
  }
}

// ---- weighted aggregation (bf16 rows, w fetched via eid from L2-resident ew) ----
__global__ void k_agg_w(const __hip_bfloat16* __restrict__ y, const float* __restrict__ r,
                        const int2* __restrict__ csr, const float* __restrict__ ew,
                        const int* __restrict__ off, float* __restrict__ out) {
  int node = blockIdx.x * 8 + threadIdx.y;
  int lane = threadIdx.x;
  int half = lane >> 5, c = lane & 31;
  int s0 = off[node], s1 = off[node + 1];
  float a0 = 0.f, a1 = 0.f;
  for (int i = s0 + half; i < s1; i += 2) {
    int2 se = csr[i];
    float w = ew[se.y];
    if (w != 0.f) {      // uniform within half-wave
      unsigned pk = *(const unsigned*)((const unsigned short*)y + (size_t)se.x * H + 2 * c);
      float v0 = __uint_as_float(pk << 16);
      float v1 = __uint_as_float(pk & 0xffff0000u);
      a0 += w * v0;
      a1 += w * v1;
    }
  }
  a0 += __shfl_xor(a0, 32);
  a1 += __shfl_xor(a1, 32);
  if (half == 0) {
    float inv = 1.f / fmaxf((float)(s1 - s0), 1.f);
    float2 rr = *((const float2*)(r + (size_t)node * H) + c);
    float2 o;
    o.x = fmaxf(a0 * inv + rr.x, 0.f);
    o.y = fmaxf(a1 * inv + rr.y, 0.f);
    *((float2*)(out + (size_t)node * H) + c) = o;
  }
}

// ---- edge scores: 16 lanes per edge, float4 coalesced rows + shfl reduce ----
__global__ void k_edge_score(const float* __restrict__ h1, const int* __restrict__ src,
                             const int* __restrict__ dst, const int* __restrict__ seg,
                             float* __restrict__ scores, unsigned* __restrict__ scoreu,
                             int* __restrict__ hist) {
  int t = blockIdx.x * 256 + threadIdx.x;
  int e = t >> 4;
  int sl = t & 15;
  if (e >= E) return;
  const float4* a = (const float4*)(h1 + (size_t)src[e] * H);
  const float4* b = (const float4*)(h1 + (size_t)dst[e] * H);
  float4 av = a[sl], bv = b[sl];
  float p = av.x * bv.x + av.y * bv.y + av.z * bv.z + av.w * bv.w;
  p += __shfl_xor(p, 1);
  p += __shfl_xor(p, 2);
  p += __shfl_xor(p, 4);
  p += __shfl_xor(p, 8);
  if (sl == 0) {
    scores[e] = p;
    unsigned u = __float_as_uint(p);
    u = (u & 0x80000000u) ? ~u : (u | 0x80000000u);
    scoreu[e] = u;
    atomicAdd(&hist[seg[e] * 256 + (int)(u >> 24)], 1);
  }
}

// ---- radix-select histogram for passes 1..3 ----
__global__ void k_hist(const unsigned* __restrict__ scoreu, const int* __restrict__ seg,
                       const unsigned* __restrict__ prefix, int* __restrict__ hist, int pass) {
  int e = blockIdx.x * 256 + threadIdx.x;
  if (e >= E) return;
  unsigned u = scoreu[e];
  int g = seg[e];
  int predshift = 32 - 8 * pass;
  if ((u >> predshift) == (prefix[g] >> predshift))
    atomicAdd(&hist[g * 256 + (int)((u >> (24 - 8 * pass)) & 0xFFu)], 1);
}

// ---- descending bucket select: one wave per graph; re-zeroes hist row ----
__global__ void k_scan(int* __restrict__ hist, const int* __restrict__ mcnt,
                       unsigned* __restrict__ prefix, int* __restrict__ krem, int pass) {
  int g = blockIdx.x;
  int lane = threadIdx.x;
  int k = (pass == 0) ? ((mcnt[g] + 1) >> 1) : krem[g];   // ceil(0.5*m)
  int4* row = (int4*)(hist + (size_t)g * 256);
  int4 v = row[lane];
  int vj[4] = {v.x, v.y, v.z, v.w};
  int s = v.x + v.y + v.z + v.w;
  int inc = s;
  for (int d = 1; d < 64; d <<= 1) {
    int t = __shfl_up(inc, d);
    if (lane >= d) inc += t;
  }
  int T = __shfl(inc, 63);
  int excl = inc - s;
  int pre[4] = {excl, excl + vj[0], excl + vj[0] + vj[1], excl + vj[0] + vj[1] + vj[2]};
  int bsel_l = -1, newk_l = 0;
  if (k > 0) {
    for (int j = 3; j >= 0; --j) {
      int suf = T - pre[j];
      if (suf >= k) { bsel_l = 4 * lane + j; newk_l = k - (suf - vj[j]); break; }
    }
  }
  unsigned long long mask = __ballot(bsel_l >= 0);
  int bsel = 255, newk = 0;
  if (k > 0 && mask) {
    int hi = 63 - __builtin_clzll(mask);
    bsel = __shfl(bsel_l, hi);
    newk = __shfl(newk_l, hi);
  }
  if (lane == 0) {
    unsigned base = (pass == 0) ? 0u : prefix[g];
    prefix[g] = base | ((unsigned)bsel << (24 - 8 * pass));
    krem[g] = newk;
  }
  row[lane] = make_int4(0, 0, 0, 0);
}

// ---- classify edges vs threshold; fully coalesced writes ----
__global__ void k_select(const unsigned* __restrict__ scoreu, const float* __restrict__ scores,
                         const int* __restrict__ seg, const unsigned* __restrict__ thresh,
                         int* __restrict__ eqcnt, int* __restrict__ eqlist,
                         float* __restrict__ sampled, float* __restrict__ ew) {
  int e = blockIdx.x * 256 + threadIdx.x;
  if (e >= E) return;
  unsigned u = scoreu[e];
  int g = seg[e];
  unsigned t = thresh[g];
  float sel = 0.f;
  if (u > t) sel = 1.f;
  else if (u == t) {
    int slot = atomicAdd(&eqcnt[g], 1);
    if (slot < CAP) eqlist[g * CAP + slot] = e;
  }
  sampled[e] = sel;
  ew[e] = scores[e] * sel;
}

// ---- resolve ties: pick r lowest-index edges among exact-threshold scores ----
__global__ void k_resolve(const int* __restrict__ krem, const int* __restrict__ eqcnt,
                          const int* __restrict__ eqlist, const float* __restrict__ scores,
                          float* __restrict__ sampled, float* __restrict__ ew) {
  int g = blockIdx.x * 256 + threadIdx.x;
  if (g >= G) return;
  int c = eqcnt[g]; if (c > CAP) c = CAP;
  int r = krem[g];  if (r > c) r = c;
  const int* lst = eqlist + g * CAP;
  int last = -1;
  for (int i = 0; i < r; ++i) {
    int mn = 0x7fffffff;
    for (int j = 0; j < c; ++j) {
      int idx = lst[j];
      if (idx > last && idx < mn) mn = idx;
    }
    if (mn == 0x7fffffff) break;
    sampled[mn] = 1.f;
    ew[mn] = scores[mn];
    last = mn;
  }
}

// ---- fused mean-pool + MLP head + log_softmax: one block per graph ----
__global__ void k_poolhead(const float* __restrict__ h3, const int* __restrict__ goff,
                           const float* __restrict__ W1, const float* __restrict__ b1,
                           const float* __restrict__ W2, const float* __restrict__ b2,
                           float* __restrict__ outp) {
  int g = blockIdx.x;
  int h = threadIdx.x;
  int s0 = goff[g], s1 = goff[g + 1];
  float a = 0.f;
  for (int n = s0; n < s1; ++n) a += h3[(size_t)n * H + h];
  float inv = 1.f / fmaxf((float)(s1 - s0), 1.f);
  __shared__ float p[H], z1[H], z2[C];
  __shared__ float lse;
  p[h] = a * inv;
  __syncthreads();
  float acc = b1[h];
#pragma unroll 8
  for (int f = 0; f < H; ++f) acc += p[f] * W1[f * H + h];
  z1[h] = fmaxf(acc, 0.f);
  __syncthreads();
  if (h < C) {
    float a2 = b2[h];
#pragma unroll 8
    for (int f = 0; f < H; ++f) a2 += z1[f] * W2[f * C + h];
    z2[h] = a2;
  }
  __syncthreads();
  if (h == 0) {
    float m = z2[0];
    for (int c = 1; c < C; ++c) m = fmaxf(m, z2[c]);
    float s = 0.f;
    for (int c = 0; c < C; ++c) s += expf(z2[c] - m);
    lse = m + logf(s);
  }
  __syncthreads();
  if (h < C) outp[(size_t)g * C + h] = z2[h] - lse;
}

extern "C" void kernel_launch(void* const* d_in, const int* in_sizes, int n_in,
                              void* d_out, int out_size, void* d_ws, size_t ws_size,
                              hipStream_t stream) {
  const float* x     = (const float*)d_in[0];
  const int*   ei    = (const int*)d_in[1];
  const int*   batch = (const int*)d_in[2];
  const float* W1l   = (const float*)d_in[3];
  const float* b1l   = (const float*)d_in[4];
  const float* W1r   = (const float*)d_in[5];
  const float* W2l   = (const float*)d_in[6];
  const float* b2l   = (const float*)d_in[7];
  const float* W2r   = (const float*)d_in[8];
  const float* W3l   = (const float*)d_in[9];
  const float* b3l   = (const float*)d_in[10];
  const float* W3r   = (const float*)d_in[11];
  const float* Wlin1 = (const float*)d_in[12];
  const float* blin1 = (const float*)d_in[13];
  const float* Wlin2 = (const float*)d_in[14];
  const float* blin2 = (const float*)d_in[15];

  const int* srcv = ei;        // edge_index row 0
  const int* dstv = ei + E;    // edge_index row 1

  float* out_ls   = (float*)d_out;       // 512*10 log_softmax
  float* out_samp = out_ls + G * C;      // 800000 sampled mask

  // ---- workspace carve (256B-aligned); zero-init block first, one memset ----
  char* w = (char*)d_ws;
  auto carve = [&](size_t bytes) { void* p = (void*)w; w += (bytes + 255) & ~(size_t)255; return p; };
  char* zbase   = w;
  int*      deg     = (int*)carve((size_t)N * 4);
  int*      mcnt    = (int*)carve((size_t)G * 4);
  int*      eqcnt   = (int*)carve((size_t)G * 4);
  int*      hist    = (int*)carve((size_t)G * 256 * 4);
  size_t    zbytes  = (size_t)(w - zbase);
  float*    h1      = (float*)carve((size_t)N * H * 4);
  float*    h2      = (float*)carve((size_t)N * H * 4);
  float*    h3      = (float*)carve((size_t)N * H * 4);
  float*    yb      = (float*)carve((size_t)N * H * 4);   // fp32 projected-left (layer 1)
  float*    rb      = (float*)carve((size_t)N * H * 4);   // fp32 projected-right
  __hip_bfloat16* ybh = (__hip_bfloat16*)carve((size_t)N * H * 2);  // bf16 table (layers 2/3)
  float*    scores  = (float*)carve((size_t)E * 4);
  unsigned* scoreu  = (unsigned*)carve((size_t)E * 4);
  int*      seg     = (int*)carve((size_t)E * 4);
  float*    ew      = (float*)carve((size_t)E * 4);       // edge-order weights
  int2*     csr     = (int2*)carve((size_t)E * 8);        // {src, eid} per slot
  int*      off     = (int*)carve((size_t)(N + 1) * 4);
  int*      cursor  = (int*)carve((size_t)N * 4);
  int*      goff    = (int*)carve((size_t)(G + 1) * 4);
  unsigned* prefix  = (unsigned*)carve((size_t)G * 4);
  int*      krem    = (int*)carve((size_t)G * 4);
  int*      eqlist  = (int*)carve((size_t)G * CAP * 4);

  hipMemsetAsync(zbase, 0, zbytes, stream);

  // ---- counts + CSR build ----
  k_deg_seg<<<128, 256, 0, stream>>>(srcv, dstv, batch, deg, seg, mcnt);
  k_goff<<<cdiv(N, 256), 256, 0, stream>>>(batch, goff);
  k_excl_scan<<<1, 1024, 0, stream>>>(deg, off, cursor, N);
  k_fill_csr<<<cdiv(E, 256), 256, 0, stream>>>(srcv, dstv, cursor, csr);

  // ---- layer 1: dense projections then fp32 gather ----
  k_gemm2<F><<<N / 16, dim3(64, 4), 0, stream>>>(x, W1l, W1r, b1l, yb, rb);
  k_agg1<<<N / 8, dim3(64, 8), 0, stream>>>(yb, rb, csr, off, h1);

  // ---- edge scores + per-graph radix top-k select ----
  k_edge_score<<<cdiv((long)E * 16, 256), 256, 0, stream>>>(h1, srcv, dstv, seg,
                                                            scores, scoreu, hist);
  k_scan<<<G, 64, 0, stream>>>(hist, mcnt, prefix, krem, 0);
  for (int p = 1; p <= 3; ++p) {
    k_hist<<<cdiv(E, 256), 256, 0, stream>>>(scoreu, seg, prefix, hist, p);
    k_scan<<<G, 64, 0, stream>>>(hist, mcnt, prefix, krem, p);
  }
  k_select<<<cdiv(E, 256), 256, 0, stream>>>(scoreu, scores, seg, prefix,
                                             eqcnt, eqlist, out_samp, ew);
  k_resolve<<<cdiv(G, 256), 256, 0, stream>>>(krem, eqcnt, eqlist, scores, out_samp, ew);

  // ---- layer 2: projections (bf16 gather table) + weighted gather ----
  k_gemm2h<H><<<N / 16, dim3(64, 4), 0, stream>>>(h1, W2l, W2r, b2l, ybh, rb);
  k_agg_w<<<N / 8, dim3(64, 8), 0, stream>>>(ybh, rb, csr, ew, off, h2);

  // ---- layer 3 ----
  k_gemm2h<H><<<N / 16, dim3(64, 4), 0, stream>>>(h2, W3l, W3r, b3l, ybh, rb);
  k_agg_w<<<N / 8, dim3(64, 8), 0, stream>>>(ybh, rb, csr, ew, off, h3);

  // ---- fused pool + head ----
  k_poolhead<<<G, 64, 0, stream>>>(h3, goff, Wlin1, blin1, Wlin2, blin2, out_ls);
}